// Round 3
// baseline (2579.387 us; speedup 1.0000x reference)
//
#include <hip/hip_runtime.h>
#include <hip/hip_bf16.h>

typedef unsigned short u16;
typedef unsigned int   u32;

// Problem constants: B=2, N=4, C=128, HEADS=8, P=4, H=W=96, TC=64, ITERS=3, HD=16
constexpr int kHW = 9216;       // 96*96
constexpr int kM  = 147456;     // 16*9216 (v/q image stride in floats; also B*HEADS*HW item count)
constexpr int EP_GELU = 1, EP_GATE = 2, EP_NET = 3, EP_QV = 4;

__device__ __forceinline__ float gelu_f(float v){ return 0.5f*v*(1.0f+erff(v*0.70710678118654752f)); }
__device__ __forceinline__ float sigm_f(float v){ return 1.0f/(1.0f+expf(-v)); }

struct Bilin { int i00,i10,i01,i11; float w00,w10,w01,w11; };

__device__ __forceinline__ Bilin make_bilin(int x, int y, float ox, float oy){
  float gx = fmaf((float)x, 2.0f/95.0f, -1.0f);
  float gy = fmaf((float)y, 2.0f/95.0f, -1.0f);
  float sgx = fminf(fmaxf(gx+ox,-1.0f),1.0f);
  float sgy = fminf(fmaxf(gy+oy,-1.0f),1.0f);
  float ix = (sgx+1.0f)*0.5f*95.0f;
  float iy = (sgy+1.0f)*0.5f*95.0f;
  float x0f = floorf(ix), y0f = floorf(iy);
  float wx = ix-x0f, wy = iy-y0f;
  int x0 = min(max((int)x0f,0),95), y0 = min(max((int)y0f,0),95);
  int x1 = min(x0+1,95), y1 = min(y0+1,95);
  Bilin b;
  b.i00=(y0*96+x0)*16; b.i10=(y0*96+x1)*16; b.i01=(y1*96+x0)*16; b.i11=(y1*96+x1)*16;
  float iwx=1.0f-wx, iwy=1.0f-wy;
  b.w00=iwx*iwy; b.w10=wx*iwy; b.w01=iwx*wy; b.w11=wx*wy;
  return b;
}

__device__ __forceinline__ void sample16(const float* __restrict__ vp, const Bilin& bl, float* __restrict__ o){
  const float4* p00 = (const float4*)(vp + bl.i00);
  const float4* p10 = (const float4*)(vp + bl.i10);
  const float4* p01 = (const float4*)(vp + bl.i01);
  const float4* p11 = (const float4*)(vp + bl.i11);
  #pragma unroll
  for (int g = 0; g < 4; ++g){
    float4 a=p00[g], b=p10[g], c=p01[g], d=p11[g];
    o[g*4+0] = a.x*bl.w00 + b.x*bl.w10 + c.x*bl.w01 + d.x*bl.w11;
    o[g*4+1] = a.y*bl.w00 + b.y*bl.w10 + c.y*bl.w01 + d.y*bl.w11;
    o[g*4+2] = a.z*bl.w00 + b.z*bl.w10 + c.z*bl.w01 + d.z*bl.w11;
    o[g*4+3] = a.w*bl.w00 + b.w*bl.w10 + c.w*bl.w01 + d.w*bl.w11;
  }
}

// ---------------- transpose the five (C,C) weight matrices into [c][o] f32 ----------------
__global__ __launch_bounds__(256) void prep_k(const float* __restrict__ qw, const float* __restrict__ vw,
    const float* __restrict__ pww, const float* __restrict__ o1w, const float* __restrict__ o2w,
    float* __restrict__ wt)
{
  const float* src = (blockIdx.y==0)?qw:(blockIdx.y==1)?vw:(blockIdx.y==2)?pww:(blockIdx.y==3)?o1w:o2w;
  float* d = wt + blockIdx.y*16384;
  int i = blockIdx.x*256 + threadIdx.x;   // grid.x = 64 -> i in [0,16384)
  int o = i & 127, c = i >> 7;
  d[i] = src[o*128 + c];                  // d[c*128+o] = w[o][c]
}

// ---------------- conv1x1: out[o] = sum_c w[o,c]*in[c] + bias[o], per pixel ----------------
// block = 256 threads = 64 px lanes x 4 o-groups (32 outputs each).
// Input tile staged in LDS (f32). Weights read from transposed f32 copy (wave-uniform broadcast).
template<int EPI>
__global__ __launch_bounds__(256) void conv1x1_k(const float* __restrict__ inp,
    const float* __restrict__ wt, const float* __restrict__ bias,
    float* __restrict__ outf, const float* __restrict__ gate)
{
  __shared__ __align__(16) float in_s[128*64];
  const int tid = threadIdx.x;
  const int img = blockIdx.y;
  const int px0 = blockIdx.x * 64;
  #pragma unroll 8
  for (int k = 0; k < 32; ++k) {
    int i = tid + 256*k;
    int c = i >> 6, p = i & 63;
    in_s[i] = inp[(img*128 + c)*kHW + px0 + p];
  }
  __syncthreads();
  const int lane = tid & 63;
  const int osub = tid >> 6;          // wave-uniform (tids 0..63 -> wave 0)
  float acc[32];
  #pragma unroll
  for (int j = 0; j < 32; ++j) acc[j] = bias[osub*32+j];
  for (int c = 0; c < 128; ++c) {
    float iv = in_s[c*64 + lane];
    const float4* wr = (const float4*)(wt + c*128 + osub*32);
    #pragma unroll
    for (int g = 0; g < 8; ++g) {
      float4 wv = wr[g];
      acc[g*4+0] = fmaf(iv, wv.x, acc[g*4+0]);
      acc[g*4+1] = fmaf(iv, wv.y, acc[g*4+1]);
      acc[g*4+2] = fmaf(iv, wv.z, acc[g*4+2]);
      acc[g*4+3] = fmaf(iv, wv.w, acc[g*4+3]);
    }
  }
  const int px = px0 + lane;
  if (EPI == EP_QV) {
    // out layout: [(img*8 + head)][px][hd16]  (head = o>>4, hd = o&15)
    #pragma unroll
    for (int h2 = 0; h2 < 2; ++h2) {
      const int head = osub*2 + h2;
      float4* dst = (float4*)(outf + (img*8 + head)*kM + px*16);
      #pragma unroll
      for (int g = 0; g < 4; ++g) {
        float4 t;
        t.x = acc[h2*16+g*4+0]; t.y = acc[h2*16+g*4+1];
        t.z = acc[h2*16+g*4+2]; t.w = acc[h2*16+g*4+3];
        dst[g] = t;
      }
    }
  } else {
    #pragma unroll
    for (int j = 0; j < 32; ++j) {
      const int o = osub*32 + j;
      float v = acc[j];
      if (EPI == EP_GELU)      outf[(img*128+o)*kHW + px] = gelu_f(v);
      else if (EPI == EP_NET)  outf[(o&15)*kM + (img*8 + (o>>4))*kHW + px] = v;  // net planar [hd][bh][yx]
      else /* EP_GATE */       outf[(img*128+o)*kHW + px] = v * sigm_f(gate[o]);  // f32 output!
    }
  }
}

// ---------------- depthwise 7x7 + bias + exact gelu ----------------
__global__ __launch_bounds__(256) void dw_k(const float* __restrict__ q, const float* __restrict__ dww,
    const float* __restrict__ dwb, float* __restrict__ outf)
{
  int idx = blockIdx.x*256 + threadIdx.x;   // B*C*HW
  int px = idx % kHW;
  int bc = idx / kHW;
  int c = bc & 127;
  int x = px % 96, y = px / 96;
  float s = dwb[c];
  const float* qb = q + bc*kHW;
  #pragma unroll
  for (int ky = 0; ky < 7; ++ky) {
    int yy = y + ky - 3;
    if (yy < 0 || yy > 95) continue;
    #pragma unroll
    for (int kx = 0; kx < 7; ++kx) {
      int xx = x + kx - 3;
      if (xx < 0 || xx > 95) continue;
      s = fmaf(qb[yy*96+xx], dww[c*49 + ky*7 + kx], s);
    }
  }
  outf[idx] = gelu_f(s);
}

// ---------------- time bias: (B,HEADS,N) ----------------
__global__ void tb_k(const float* __restrict__ te, const float* __restrict__ tw,
                     const float* __restrict__ tbias, float* __restrict__ tbb)
{
  int i = threadIdx.x;
  if (i >= 64) return;
  int b = i >> 5, h = (i >> 2) & 7, n = i & 3;
  float s = tbias[h];
  for (int tc = 0; tc < 64; ++tc) s = fmaf(te[(b*4+n)*64 + tc], tw[h*64+tc], s);
  tbb[(b*8+h)*4 + n] = s;
}

// ---------------- correlation argmax -> initial offsets, zero attn ----------------
__global__ __launch_bounds__(256) void corr_k(const float* __restrict__ qb, const float* __restrict__ vs,
    const float* __restrict__ relt, float* __restrict__ off, float* __restrict__ attn)
{
  int item = blockIdx.x*256 + threadIdx.x;
  int yx = item % kHW; int bh = item / kHW;
  int b = bh >> 3, head = bh & 7;
  int x = yx % 96, y = yx / 96;
  int nidx = 0;
  { float bv = fabsf(relt[b*4]);
    for (int n = 1; n < 4; ++n){ float a = fabsf(relt[b*4+n]); if (a < bv){ bv=a; nidx=n; } } }
  const float* qp = qb + bh*kM + yx*16;
  float qv[16];
  { const float4* q4 = (const float4*)qp;
    #pragma unroll
    for (int g = 0; g < 4; ++g){ float4 t = q4[g]; qv[g*4]=t.x; qv[g*4+1]=t.y; qv[g*4+2]=t.z; qv[g*4+3]=t.w; } }
  const float* vp = vs + ((b*4+nidx)*8 + head)*kM;
  const int sdx[5] = {0,-1,1,0,0};   // SHIFTS entries are (dx,dy)
  const int sdy[5] = {0,0,0,-1,1};
  double bsc = 0.0; int best = 0;
  #pragma unroll
  for (int s5 = 0; s5 < 5; ++s5) {
    int sy = y - sdy[s5], sx = x - sdx[s5];
    double sc = 0.0;
    if (sy >= 0 && sy < 96 && sx >= 0 && sx < 96) {
      const float* tp = vp + (sy*96+sx)*16;
      #pragma unroll
      for (int hd = 0; hd < 16; ++hd) sc += (double)qv[hd]*(double)tp[hd];
    }
    if (s5 == 0) { bsc = sc; best = 0; }
    else if (sc > bsc) { bsc = sc; best = s5; }   // strict >: first-max wins, matches argmax
  }
  const float STEP = 2.0f/96.0f;
  float ox = 0.f, oy = 0.f;          // reference swap: x-offset = dy*2/W, y-offset = dx*2/H
  if (best == 3) ox = -STEP; else if (best == 4) ox = STEP;
  if (best == 1) oy = -STEP; else if (best == 2) oy = STEP;
  #pragma unroll
  for (int p = 0; p < 4; ++p) {
    off[(2*p)*kM + item]   = ox;
    off[(2*p+1)*kM + item] = oy;
    attn[p*kM + item] = 0.0f;
  }
}

// ---------------- one GRU refinement iteration ----------------
__global__ __launch_bounds__(256) void iter_k(
    const float* __restrict__ vs, const float* __restrict__ relt,
    const float* __restrict__ wih, const float* __restrict__ whh,
    const float* __restrict__ bih, const float* __restrict__ bhh,
    const float* __restrict__ offw, const float* __restrict__ offbp,
    const float* __restrict__ aw, const float* __restrict__ abp,
    float* __restrict__ net, float* __restrict__ off, float* __restrict__ attn)
{
  __shared__ __align__(16) float s_wih[48*20];   // rows padded 18->20 (pad=0)
  __shared__ __align__(16) float s_whh[48*16];
  __shared__ __align__(16) float s_offw[8*16];
  __shared__ __align__(16) float s_aw[4*16];
  __shared__ float s_bih[48], s_bhh[48], s_offb[8], s_ab[4];
  const int tid = threadIdx.x;
  for (int i = tid; i < 960; i += 256){ int g = i/20, k = i%20; s_wih[i] = (k<18)? wih[g*18+k] : 0.0f; }
  for (int i = tid; i < 768; i += 256) s_whh[i] = whh[i];
  if (tid < 128) s_offw[tid] = offw[tid];
  if (tid < 64)  s_aw[tid]  = aw[tid];
  if (tid < 48){ s_bih[tid] = bih[tid]; s_bhh[tid] = bhh[tid]; }
  if (tid < 8)   s_offb[tid] = offbp[tid];
  if (tid < 4)   s_ab[tid]  = abp[tid];
  __syncthreads();

  const int item = blockIdx.x*256 + tid;
  const int yx = item % kHW; const int bh = item / kHW;
  const int b = bh >> 3, head = bh & 7;
  const int x = yx % 96, y = yx / 96;
  int nidx = 0;
  { float bv = fabsf(relt[b*4]);
    for (int n = 1; n < 4; ++n){ float a = fabsf(relt[b*4+n]); if (a < bv){ bv=a; nidx=n; } } }
  const float p0x = off[item];
  const float p0y = off[kM + item];
  Bilin bl = make_bilin(x, y, p0x, p0y);
  const float* vp = vs + ((b*4+nidx)*8 + head)*kM;
  float xv[20];
  sample16(vp, bl, xv);
  xv[16] = p0x; xv[17] = p0y; xv[18] = 0.f; xv[19] = 0.f;
  float h[16];
  #pragma unroll
  for (int j = 0; j < 16; ++j) h[j] = net[j*kM + item];

  float grz[32], gin[16], ghn[16];
  #pragma unroll
  for (int g = 0; g < 48; ++g) {
    const float4* wr = (const float4*)&s_wih[g*20];
    float s = s_bih[g];
    #pragma unroll
    for (int q4 = 0; q4 < 5; ++q4) {
      float4 w4 = wr[q4];
      s = fmaf(xv[q4*4+0], w4.x, s); s = fmaf(xv[q4*4+1], w4.y, s);
      s = fmaf(xv[q4*4+2], w4.z, s); s = fmaf(xv[q4*4+3], w4.w, s);
    }
    const float4* hr = (const float4*)&s_whh[g*16];
    float s2 = s_bhh[g];
    #pragma unroll
    for (int q4 = 0; q4 < 4; ++q4) {
      float4 w4 = hr[q4];
      s2 = fmaf(h[q4*4+0], w4.x, s2); s2 = fmaf(h[q4*4+1], w4.y, s2);
      s2 = fmaf(h[q4*4+2], w4.z, s2); s2 = fmaf(h[q4*4+3], w4.w, s2);
    }
    if (g < 32) grz[g] = s + s2;
    else { gin[g-32] = s; ghn[g-32] = s2; }
  }
  float hn[16];
  #pragma unroll
  for (int j = 0; j < 16; ++j) {
    float r = sigm_f(grz[j]);
    float z = sigm_f(grz[16+j]);
    float nn = tanhf(fmaf(r, ghn[j], gin[j]));
    hn[j] = fmaf(z, h[j], (1.0f - z)*nn);
  }
  #pragma unroll
  for (int j = 0; j < 16; ++j) net[j*kM + item] = hn[j];
  #pragma unroll
  for (int d = 0; d < 8; ++d) {
    const float4* wr = (const float4*)&s_offw[d*16];
    float s = s_offb[d];
    #pragma unroll
    for (int q4 = 0; q4 < 4; ++q4) {
      float4 w4 = wr[q4];
      s = fmaf(hn[q4*4+0], w4.x, s); s = fmaf(hn[q4*4+1], w4.y, s);
      s = fmaf(hn[q4*4+2], w4.z, s); s = fmaf(hn[q4*4+3], w4.w, s);
    }
    off[d*kM + item] += s;
  }
  #pragma unroll
  for (int p = 0; p < 4; ++p) {
    const float4* wr = (const float4*)&s_aw[p*16];
    float s = s_ab[p];
    #pragma unroll
    for (int q4 = 0; q4 < 4; ++q4) {
      float4 w4 = wr[q4];
      s = fmaf(hn[q4*4+0], w4.x, s); s = fmaf(hn[q4*4+1], w4.y, s);
      s = fmaf(hn[q4*4+2], w4.z, s); s = fmaf(hn[q4*4+3], w4.w, s);
    }
    attn[p*kM + item] += s;
  }
}

// ---------------- softmax + N*P deformable sampling + weighted sum + entropy ----------------
__global__ __launch_bounds__(256) void final_k(
    const float* __restrict__ vs, const float* __restrict__ off,
    const float* __restrict__ attn, const float* __restrict__ tbb,
    float* __restrict__ outattn, float* __restrict__ entb)
{
  const int item = blockIdx.x*256 + threadIdx.x;
  const int yx = item % kHW; const int bh = item / kHW;
  const int b = bh >> 3, head = bh & 7;
  const int x = yx % 96, y = yx / 96;
  float lg[16];
  #pragma unroll
  for (int p = 0; p < 4; ++p) {
    float ap = attn[p*kM + item];
    #pragma unroll
    for (int n = 0; n < 4; ++n) lg[n*4+p] = ap;
  }
  #pragma unroll
  for (int n = 0; n < 4; ++n) {
    float tv = tbb[(b*8+head)*4 + n];
    #pragma unroll
    for (int p = 0; p < 4; ++p) lg[n*4+p] += tv;
  }
  float mx = lg[0];
  #pragma unroll
  for (int i = 1; i < 16; ++i) mx = fmaxf(mx, lg[i]);
  float es = 0.f;
  #pragma unroll
  for (int i = 0; i < 16; ++i){ lg[i] = expf(lg[i]-mx); es += lg[i]; }
  float inv = 1.0f/es;
  float ent = 0.f;
  #pragma unroll
  for (int i = 0; i < 16; ++i){ lg[i] *= inv; ent -= lg[i]*logf(lg[i] + 1e-8f); }
  entb[item] = ent;

  float acc[16];
  #pragma unroll
  for (int j = 0; j < 16; ++j) acc[j] = 0.f;
  #pragma unroll
  for (int p = 0; p < 4; ++p) {
    float ox = off[(2*p)*kM + item];
    float oy = off[(2*p+1)*kM + item];
    Bilin bl = make_bilin(x, y, ox, oy);
    #pragma unroll
    for (int n = 0; n < 4; ++n) {
      const float* vp = vs + ((b*4+n)*8 + head)*kM;
      float smp[16];
      sample16(vp, bl, smp);
      float wnp = lg[n*4+p];
      #pragma unroll
      for (int j = 0; j < 16; ++j) acc[j] = fmaf(wnp, smp[j], acc[j]);
    }
  }
  const int obase = (b*128 + head*16)*kHW + yx;
  #pragma unroll
  for (int j = 0; j < 16; ++j) outattn[obase + j*kHW] = acc[j];
}

// ---------------- entropy mean over heads -> confidence/entropy outputs (f32) ----------------
__global__ __launch_bounds__(256) void ent_k(const float* __restrict__ entb, float* __restrict__ outf)
{
  int idx = blockIdx.x*256 + threadIdx.x;   // B*HW = 18432
  int b = idx / kHW, yx = idx % kHW;
  float s = 0.f;
  #pragma unroll
  for (int h8 = 0; h8 < 8; ++h8) s += entb[(b*8+h8)*kHW + yx];
  s *= 0.125f;
  float conf = 1.0f - fminf(fmaxf(s / (2.772588722239781f + 1e-8f), 0.0f), 1.0f);
  outf[2359296 + idx]         = conf;
  outf[2359296 + 18432 + idx] = s;
}

extern "C" void kernel_launch(void* const* d_in, const int* in_sizes, int n_in,
                              void* d_out, int out_size, void* d_ws, size_t ws_size,
                              hipStream_t stream)
{
  const float* query  = (const float*)d_in[0];
  const float* values = (const float*)d_in[1];
  const float* relt   = (const float*)d_in[2];
  const float* time_enc = (const float*)d_in[3];
  const float* qw  = (const float*)d_in[4];
  const float* qb  = (const float*)d_in[5];
  const float* vw  = (const float*)d_in[6];
  const float* vb  = (const float*)d_in[7];
  const float* dww = (const float*)d_in[8];
  const float* dwb = (const float*)d_in[9];
  const float* pww = (const float*)d_in[10];
  const float* pwb = (const float*)d_in[11];
  const float* wih = (const float*)d_in[12];
  const float* whh = (const float*)d_in[13];
  const float* bih = (const float*)d_in[14];
  const float* bhh = (const float*)d_in[15];
  const float* offw = (const float*)d_in[16];
  const float* offb = (const float*)d_in[17];
  const float* aw  = (const float*)d_in[18];
  const float* ab  = (const float*)d_in[19];
  const float* tw  = (const float*)d_in[20];
  const float* tb  = (const float*)d_in[21];
  const float* o1w = (const float*)d_in[22];
  const float* o1b = (const float*)d_in[23];
  const float* o2w = (const float*)d_in[24];
  const float* o2b = (const float*)d_in[25];
  const float* gate = (const float*)d_in[26];
  float* out = (float*)d_out;
  float* ws = (float*)d_ws;

  // workspace layout (f32 elements)
  float* vsb    = ws;                 // v in [(b,n,head)][yx][hd16] : 9437184
  float* qbuf   = ws +  9437184;      // q in [(b,head)][yx][hd16]  : 2359296 ; reused as outattn
  float* netb   = ws + 11796480;      // net planar [hd][bh][yx]    : 2359296
  float* dwbuf  = ws + 14155776;      // depthwise out [b][c][yx]   : 2359296 ; reused as mid
  float* offbuf = ws + 16515072;      // offsets planar [p*2+d][item]: 1179648
  float* atbuf  = ws + 17694720;      // attn planar [p][item]      :  589824
  float* entbf  = ws + 18284544;      // per-head entropy [item]    :  147456
  float* tbbuf  = ws + 18432000;      // time bias (B,H,N)          :      64
  float* wtbuf  = ws + 18432064;      // 5 transposed weights       :   81920
  if (ws_size < 18513984ull * 4ull) return;   // ~74.1 MB required

  float* wt_q  = wtbuf;
  float* wt_v  = wtbuf + 16384;
  float* wt_pw = wtbuf + 32768;
  float* wt_o1 = wtbuf + 49152;
  float* wt_o2 = wtbuf + 65536;

  dim3 blk(256,1,1);
  // 0. transpose weights
  prep_k<<<dim3(64,5,1), blk, 0, stream>>>(qw, vw, pww, o1w, o2w, wtbuf);
  // 1. q = conv1x1(query)
  conv1x1_k<EP_QV><<<dim3(144,2,1), blk, 0, stream>>>(query, wt_q, qb, qbuf, nullptr);
  // 2. v = conv1x1(values), sampling-friendly layout
  conv1x1_k<EP_QV><<<dim3(144,8,1), blk, 0, stream>>>(values, wt_v, vb, vsb, nullptr);
  // 3. depthwise 7x7 + gelu
  dw_k<<<dim3(9216,1,1), blk, 0, stream>>>(query, dww, dwb, dwbuf);
  // 4. pointwise -> initial GRU state (planar)
  conv1x1_k<EP_NET><<<dim3(144,2,1), blk, 0, stream>>>(dwbuf, wt_pw, pwb, netb, nullptr);
  // 5. time bias
  tb_k<<<dim3(1,1,1), dim3(64,1,1), 0, stream>>>(time_enc, tw, tb, tbbuf);
  // 6. correlation argmax -> initial offsets, zero attn
  corr_k<<<dim3(576,1,1), blk, 0, stream>>>(qbuf, vsb, relt, offbuf, atbuf);
  // 7-9. three GRU refinement iterations
  for (int it = 0; it < 3; ++it)
    iter_k<<<dim3(576,1,1), blk, 0, stream>>>(vsb, relt, wih, whh, bih, bhh, offw, offb, aw, ab,
                                              netb, offbuf, atbuf);
  // 10. softmax + sampling + weighted sum (writes outattn into qbuf) + per-head entropy
  final_k<<<dim3(576,1,1), blk, 0, stream>>>(vsb, offbuf, atbuf, tbbuf, qbuf, entbf);
  // 11. entropy mean / confidence -> d_out tail (f32)
  ent_k<<<dim3(72,1,1), blk, 0, stream>>>(entbf, out);
  // 12. o1 + gelu (into dwbuf as mid)
  conv1x1_k<EP_GELU><<<dim3(144,2,1), blk, 0, stream>>>(qbuf, wt_o1, o1b, dwbuf, nullptr);
  // 13. o2 * sigmoid(gate) -> f32 d_out
  conv1x1_k<EP_GATE><<<dim3(144,2,1), blk, 0, stream>>>(dwbuf, wt_o2, o2b, out, gate);
}

// Round 4
// 996.507 us; speedup vs baseline: 2.5884x; 2.5884x over previous
//
#include <hip/hip_runtime.h>
#include <hip/hip_bf16.h>

typedef unsigned short u16;
typedef unsigned int   u32;

// Problem constants: B=2, N=4, C=128, HEADS=8, P=4, H=W=96, TC=64, ITERS=3, HD=16
constexpr int kHW = 9216;       // 96*96
constexpr int kM  = 147456;     // 16*9216 (v/q image stride in floats; also B*HEADS*HW item count)
constexpr int EP_GELU = 1, EP_GATE = 2, EP_NET = 3, EP_QV = 4;

__device__ __forceinline__ float gelu_f(float v){ return 0.5f*v*(1.0f+erff(v*0.70710678118654752f)); }
__device__ __forceinline__ float sigm_f(float v){ return 1.0f/(1.0f+expf(-v)); }

struct Bilin { int i00,i10,i01,i11; float w00,w10,w01,w11; };

__device__ __forceinline__ Bilin make_bilin(int x, int y, float ox, float oy){
  float gx = fmaf((float)x, 2.0f/95.0f, -1.0f);
  float gy = fmaf((float)y, 2.0f/95.0f, -1.0f);
  float sgx = fminf(fmaxf(gx+ox,-1.0f),1.0f);
  float sgy = fminf(fmaxf(gy+oy,-1.0f),1.0f);
  float ix = (sgx+1.0f)*0.5f*95.0f;
  float iy = (sgy+1.0f)*0.5f*95.0f;
  float x0f = floorf(ix), y0f = floorf(iy);
  float wx = ix-x0f, wy = iy-y0f;
  int x0 = min(max((int)x0f,0),95), y0 = min(max((int)y0f,0),95);
  int x1 = min(x0+1,95), y1 = min(y0+1,95);
  Bilin b;
  b.i00=(y0*96+x0)*16; b.i10=(y0*96+x1)*16; b.i01=(y1*96+x0)*16; b.i11=(y1*96+x1)*16;
  float iwx=1.0f-wx, iwy=1.0f-wy;
  b.w00=iwx*iwy; b.w10=wx*iwy; b.w01=iwx*wy; b.w11=wx*wy;
  return b;
}

__device__ __forceinline__ void sample16(const float* __restrict__ vp, const Bilin& bl, float* __restrict__ o){
  const float4* p00 = (const float4*)(vp + bl.i00);
  const float4* p10 = (const float4*)(vp + bl.i10);
  const float4* p01 = (const float4*)(vp + bl.i01);
  const float4* p11 = (const float4*)(vp + bl.i11);
  #pragma unroll
  for (int g = 0; g < 4; ++g){
    float4 a=p00[g], b=p10[g], c=p01[g], d=p11[g];
    o[g*4+0] = a.x*bl.w00 + b.x*bl.w10 + c.x*bl.w01 + d.x*bl.w11;
    o[g*4+1] = a.y*bl.w00 + b.y*bl.w10 + c.y*bl.w01 + d.y*bl.w11;
    o[g*4+2] = a.z*bl.w00 + b.z*bl.w10 + c.z*bl.w01 + d.z*bl.w11;
    o[g*4+3] = a.w*bl.w00 + b.w*bl.w10 + c.w*bl.w01 + d.w*bl.w11;
  }
}

// ---------------- transpose the five (C,C) weight matrices into [c][o] f32 ----------------
__global__ __launch_bounds__(256) void prep_k(const float* __restrict__ qw, const float* __restrict__ vw,
    const float* __restrict__ pww, const float* __restrict__ o1w, const float* __restrict__ o2w,
    float* __restrict__ wt)
{
  const float* src = (blockIdx.y==0)?qw:(blockIdx.y==1)?vw:(blockIdx.y==2)?pww:(blockIdx.y==3)?o1w:o2w;
  float* d = wt + blockIdx.y*16384;
  int i = blockIdx.x*256 + threadIdx.x;   // grid.x = 64 -> i in [0,16384)
  int o = i & 127, c = i >> 7;
  d[i] = src[o*128 + c];                  // d[c*128+o] = w[o][c]
}

// ---------------- conv1x1: out[o] = sum_c w[o,c]*in[c] + bias[o], per pixel ----------------
template<int EPI>
__global__ __launch_bounds__(256) void conv1x1_k(const float* __restrict__ inp,
    const float* __restrict__ wt, const float* __restrict__ bias,
    float* __restrict__ outf, const float* __restrict__ gate)
{
  __shared__ __align__(16) float in_s[128*64];
  const int tid = threadIdx.x;
  const int img = blockIdx.y;
  const int px0 = blockIdx.x * 64;
  #pragma unroll 8
  for (int k = 0; k < 32; ++k) {
    int i = tid + 256*k;
    int c = i >> 6, p = i & 63;
    in_s[i] = inp[(img*128 + c)*kHW + px0 + p];
  }
  __syncthreads();
  const int lane = tid & 63;
  const int osub = tid >> 6;          // wave-uniform
  float acc[32];
  #pragma unroll
  for (int j = 0; j < 32; ++j) acc[j] = bias[osub*32+j];
  for (int c = 0; c < 128; ++c) {
    float iv = in_s[c*64 + lane];
    const float4* wr = (const float4*)(wt + c*128 + osub*32);
    #pragma unroll
    for (int g = 0; g < 8; ++g) {
      float4 wv = wr[g];
      acc[g*4+0] = fmaf(iv, wv.x, acc[g*4+0]);
      acc[g*4+1] = fmaf(iv, wv.y, acc[g*4+1]);
      acc[g*4+2] = fmaf(iv, wv.z, acc[g*4+2]);
      acc[g*4+3] = fmaf(iv, wv.w, acc[g*4+3]);
    }
  }
  const int px = px0 + lane;
  if (EPI == EP_QV) {
    #pragma unroll
    for (int h2 = 0; h2 < 2; ++h2) {
      const int head = osub*2 + h2;
      float4* dst = (float4*)(outf + (img*8 + head)*kM + px*16);
      #pragma unroll
      for (int g = 0; g < 4; ++g) {
        float4 t;
        t.x = acc[h2*16+g*4+0]; t.y = acc[h2*16+g*4+1];
        t.z = acc[h2*16+g*4+2]; t.w = acc[h2*16+g*4+3];
        dst[g] = t;
      }
    }
  } else {
    #pragma unroll
    for (int j = 0; j < 32; ++j) {
      const int o = osub*32 + j;
      float v = acc[j];
      if (EPI == EP_GELU)      outf[(img*128+o)*kHW + px] = gelu_f(v);
      else if (EPI == EP_NET)  outf[(o&15)*kM + (img*8 + (o>>4))*kHW + px] = v;  // net planar [hd][bh][yx]
      else /* EP_GATE */       outf[(img*128+o)*kHW + px] = v * sigm_f(gate[o]);
    }
  }
}

// ---------------- depthwise 7x7 + bias + exact gelu ----------------
__global__ __launch_bounds__(256) void dw_k(const float* __restrict__ q, const float* __restrict__ dww,
    const float* __restrict__ dwb, float* __restrict__ outf)
{
  int idx = blockIdx.x*256 + threadIdx.x;   // B*C*HW
  int px = idx % kHW;
  int bc = idx / kHW;
  int c = bc & 127;
  int x = px % 96, y = px / 96;
  float s = dwb[c];
  const float* qb = q + bc*kHW;
  #pragma unroll
  for (int ky = 0; ky < 7; ++ky) {
    int yy = y + ky - 3;
    if (yy < 0 || yy > 95) continue;
    #pragma unroll
    for (int kx = 0; kx < 7; ++kx) {
      int xx = x + kx - 3;
      if (xx < 0 || xx > 95) continue;
      s = fmaf(qb[yy*96+xx], dww[c*49 + ky*7 + kx], s);
    }
  }
  outf[idx] = gelu_f(s);
}

// ---------------- time bias: (B,HEADS,N) ----------------
__global__ void tb_k(const float* __restrict__ te, const float* __restrict__ tw,
                     const float* __restrict__ tbias, float* __restrict__ tbb)
{
  int i = threadIdx.x;
  if (i >= 64) return;
  int b = i >> 5, h = (i >> 2) & 7, n = i & 3;
  float s = tbias[h];
  for (int tc = 0; tc < 64; ++tc) s = fmaf(te[(b*4+n)*64 + tc], tw[h*64+tc], s);
  tbb[(b*8+h)*4 + n] = s;
}

// ---------------- FUSED: correlation argmax + 3 GRU iterations + softmax/sampling/entropy ----
// Per-item independent: net[16], off[8], attn[4] live in registers across all stages.
__global__ __launch_bounds__(256, 3) void fused_k(
    const float* __restrict__ qb, const float* __restrict__ vs,
    const float* __restrict__ netb, const float* __restrict__ relt,
    const float* __restrict__ wih, const float* __restrict__ whh,
    const float* __restrict__ bihp, const float* __restrict__ bhhp,
    const float* __restrict__ offw, const float* __restrict__ offbp,
    const float* __restrict__ aw, const float* __restrict__ abp,
    const float* __restrict__ tbb,
    float* __restrict__ outattn, float* __restrict__ entb)
{
  __shared__ __align__(16) float s_wih[48*20];   // rows padded 18->20 (pad=0)
  __shared__ __align__(16) float s_whh[48*16];
  __shared__ __align__(16) float s_offw[8*16];
  __shared__ __align__(16) float s_aw[4*16];
  __shared__ float s_bih[48], s_bhh[48], s_offb[8], s_ab[4];
  const int tid = threadIdx.x;
  for (int i = tid; i < 960; i += 256){ int g = i/20, k = i%20; s_wih[i] = (k<18)? wih[g*18+k] : 0.0f; }
  for (int i = tid; i < 768; i += 256) s_whh[i] = whh[i];
  if (tid < 128) s_offw[tid] = offw[tid];
  if (tid < 64)  s_aw[tid]  = aw[tid];
  if (tid < 48){ s_bih[tid] = bihp[tid]; s_bhh[tid] = bhhp[tid]; }
  if (tid < 8)   s_offb[tid] = offbp[tid];
  if (tid < 4)   s_ab[tid]  = abp[tid];

  const int item = blockIdx.x*256 + tid;
  const int yx = item % kHW; const int bh = item / kHW;
  const int b = bh >> 3, head = bh & 7;
  const int x = yx % 96, y = yx / 96;
  int nidx = 0;
  { float bv = fabsf(relt[b*4]);
    for (int n = 1; n < 4; ++n){ float a = fabsf(relt[b*4+n]); if (a < bv){ bv=a; nidx=n; } } }
  const float* vp = vs + ((b*4+nidx)*8 + head)*kM;

  // ---- correlation argmax (f64 accumulation, matches numpy ordering) ----
  float off_[8], attn_[4];
  {
    float qv[16];
    { const float4* q4 = (const float4*)(qb + bh*kM + yx*16);
      #pragma unroll
      for (int g = 0; g < 4; ++g){ float4 t = q4[g]; qv[g*4]=t.x; qv[g*4+1]=t.y; qv[g*4+2]=t.z; qv[g*4+3]=t.w; } }
    const int sdx[5] = {0,-1,1,0,0};   // SHIFTS entries are (dx,dy)
    const int sdy[5] = {0,0,0,-1,1};
    double bsc = 0.0; int best = 0;
    #pragma unroll
    for (int s5 = 0; s5 < 5; ++s5) {
      int sy = y - sdy[s5], sx = x - sdx[s5];
      double sc = 0.0;
      if (sy >= 0 && sy < 96 && sx >= 0 && sx < 96) {
        const float* tp = vp + (sy*96+sx)*16;
        #pragma unroll
        for (int hd = 0; hd < 16; ++hd) sc += (double)qv[hd]*(double)tp[hd];
      }
      if (s5 == 0) { bsc = sc; best = 0; }
      else if (sc > bsc) { bsc = sc; best = s5; }
    }
    const float STEP = 2.0f/96.0f;
    float ox = 0.f, oy = 0.f;        // reference swap: x-offset = dy*2/W, y-offset = dx*2/H
    if (best == 3) ox = -STEP; else if (best == 4) ox = STEP;
    if (best == 1) oy = -STEP; else if (best == 2) oy = STEP;
    #pragma unroll
    for (int p = 0; p < 4; ++p) { off_[2*p] = ox; off_[2*p+1] = oy; attn_[p] = 0.0f; }
  }

  float h[16];
  #pragma unroll
  for (int j = 0; j < 16; ++j) h[j] = netb[j*kM + item];

  __syncthreads();   // LDS weights ready

  // ---- 3 GRU refinement iterations, all state in registers ----
  for (int it = 0; it < 3; ++it) {
    const float p0x = off_[0];
    const float p0y = off_[1];
    Bilin bl = make_bilin(x, y, p0x, p0y);
    float xv[20];
    sample16(vp, bl, xv);
    xv[16] = p0x; xv[17] = p0y; xv[18] = 0.f; xv[19] = 0.f;

    float hn[16];
    #pragma unroll 2
    for (int j = 0; j < 16; ++j) {
      // input-hidden gates: rows j (r), 16+j (z), 32+j (n); bias-first, k ascending (matches prior order)
      float g0 = s_bih[j], g1 = s_bih[16+j], g2 = s_bih[32+j];
      const float4* w0r = (const float4*)&s_wih[j*20];
      const float4* w1r = (const float4*)&s_wih[(16+j)*20];
      const float4* w2r = (const float4*)&s_wih[(32+j)*20];
      #pragma unroll
      for (int q4 = 0; q4 < 5; ++q4) {
        float4 w0 = w0r[q4], w1 = w1r[q4], w2 = w2r[q4];
        float a0 = xv[q4*4+0], a1 = xv[q4*4+1], a2 = xv[q4*4+2], a3 = xv[q4*4+3];
        g0 = fmaf(a0,w0.x,g0); g0 = fmaf(a1,w0.y,g0); g0 = fmaf(a2,w0.z,g0); g0 = fmaf(a3,w0.w,g0);
        g1 = fmaf(a0,w1.x,g1); g1 = fmaf(a1,w1.y,g1); g1 = fmaf(a2,w1.z,g1); g1 = fmaf(a3,w1.w,g1);
        g2 = fmaf(a0,w2.x,g2); g2 = fmaf(a1,w2.y,g2); g2 = fmaf(a2,w2.z,g2); g2 = fmaf(a3,w2.w,g2);
      }
      float t0 = s_bhh[j], t1 = s_bhh[16+j], t2 = s_bhh[32+j];
      const float4* h0r = (const float4*)&s_whh[j*16];
      const float4* h1r = (const float4*)&s_whh[(16+j)*16];
      const float4* h2r = (const float4*)&s_whh[(32+j)*16];
      #pragma unroll
      for (int q4 = 0; q4 < 4; ++q4) {
        float4 w0 = h0r[q4], w1 = h1r[q4], w2 = h2r[q4];
        float a0 = h[q4*4+0], a1 = h[q4*4+1], a2 = h[q4*4+2], a3 = h[q4*4+3];
        t0 = fmaf(a0,w0.x,t0); t0 = fmaf(a1,w0.y,t0); t0 = fmaf(a2,w0.z,t0); t0 = fmaf(a3,w0.w,t0);
        t1 = fmaf(a0,w1.x,t1); t1 = fmaf(a1,w1.y,t1); t1 = fmaf(a2,w1.z,t1); t1 = fmaf(a3,w1.w,t1);
        t2 = fmaf(a0,w2.x,t2); t2 = fmaf(a1,w2.y,t2); t2 = fmaf(a2,w2.z,t2); t2 = fmaf(a3,w2.w,t2);
      }
      float r = sigm_f(g0 + t0);
      float z = sigm_f(g1 + t1);
      float nn = tanhf(fmaf(r, t2, g2));
      hn[j] = fmaf(z, h[j], (1.0f - z)*nn);
    }
    #pragma unroll
    for (int j = 0; j < 16; ++j) h[j] = hn[j];

    #pragma unroll
    for (int d = 0; d < 8; ++d) {
      const float4* wr = (const float4*)&s_offw[d*16];
      float s = s_offb[d];
      #pragma unroll
      for (int q4 = 0; q4 < 4; ++q4) {
        float4 w4 = wr[q4];
        s = fmaf(h[q4*4+0], w4.x, s); s = fmaf(h[q4*4+1], w4.y, s);
        s = fmaf(h[q4*4+2], w4.z, s); s = fmaf(h[q4*4+3], w4.w, s);
      }
      off_[d] += s;
    }
    #pragma unroll
    for (int p = 0; p < 4; ++p) {
      const float4* wr = (const float4*)&s_aw[p*16];
      float s = s_ab[p];
      #pragma unroll
      for (int q4 = 0; q4 < 4; ++q4) {
        float4 w4 = wr[q4];
        s = fmaf(h[q4*4+0], w4.x, s); s = fmaf(h[q4*4+1], w4.y, s);
        s = fmaf(h[q4*4+2], w4.z, s); s = fmaf(h[q4*4+3], w4.w, s);
      }
      attn_[p] += s;
    }
  }

  // ---- softmax over (N,P) + entropy ----
  float lg[16];
  #pragma unroll
  for (int n = 0; n < 4; ++n) {
    float tv = tbb[(b*8+head)*4 + n];
    #pragma unroll
    for (int p = 0; p < 4; ++p) lg[n*4+p] = attn_[p] + tv;
  }
  float mx = lg[0];
  #pragma unroll
  for (int i = 1; i < 16; ++i) mx = fmaxf(mx, lg[i]);
  float es = 0.f;
  #pragma unroll
  for (int i = 0; i < 16; ++i){ lg[i] = expf(lg[i]-mx); es += lg[i]; }
  float inv = 1.0f/es;
  float ent = 0.f;
  #pragma unroll
  for (int i = 0; i < 16; ++i){ lg[i] *= inv; ent -= lg[i]*logf(lg[i] + 1e-8f); }
  entb[item] = ent;

  // ---- N*P deformable sampling + weighted sum ----
  float acc[16];
  #pragma unroll
  for (int j = 0; j < 16; ++j) acc[j] = 0.f;
  #pragma unroll
  for (int p = 0; p < 4; ++p) {
    Bilin bl = make_bilin(x, y, off_[2*p], off_[2*p+1]);
    #pragma unroll
    for (int n = 0; n < 4; ++n) {
      const float* vpn = vs + ((b*4+n)*8 + head)*kM;
      float smp[16];
      sample16(vpn, bl, smp);
      float wnp = lg[n*4+p];
      #pragma unroll
      for (int j = 0; j < 16; ++j) acc[j] = fmaf(wnp, smp[j], acc[j]);
    }
  }
  const int obase = (b*128 + head*16)*kHW + yx;
  #pragma unroll
  for (int j = 0; j < 16; ++j) outattn[obase + j*kHW] = acc[j];
}

// ---------------- entropy mean over heads -> confidence/entropy outputs (f32) ----------------
__global__ __launch_bounds__(256) void ent_k(const float* __restrict__ entb, float* __restrict__ outf)
{
  int idx = blockIdx.x*256 + threadIdx.x;   // B*HW = 18432
  int b = idx / kHW, yx = idx % kHW;
  float s = 0.f;
  #pragma unroll
  for (int h8 = 0; h8 < 8; ++h8) s += entb[(b*8+h8)*kHW + yx];
  s *= 0.125f;
  float conf = 1.0f - fminf(fmaxf(s / (2.772588722239781f + 1e-8f), 0.0f), 1.0f);
  outf[2359296 + idx]         = conf;
  outf[2359296 + 18432 + idx] = s;
}

extern "C" void kernel_launch(void* const* d_in, const int* in_sizes, int n_in,
                              void* d_out, int out_size, void* d_ws, size_t ws_size,
                              hipStream_t stream)
{
  const float* query  = (const float*)d_in[0];
  const float* values = (const float*)d_in[1];
  const float* relt   = (const float*)d_in[2];
  const float* time_enc = (const float*)d_in[3];
  const float* qw  = (const float*)d_in[4];
  const float* qb  = (const float*)d_in[5];
  const float* vw  = (const float*)d_in[6];
  const float* vb  = (const float*)d_in[7];
  const float* dww = (const float*)d_in[8];
  const float* dwb = (const float*)d_in[9];
  const float* pww = (const float*)d_in[10];
  const float* pwb = (const float*)d_in[11];
  const float* wih = (const float*)d_in[12];
  const float* whh = (const float*)d_in[13];
  const float* bih = (const float*)d_in[14];
  const float* bhh = (const float*)d_in[15];
  const float* offw = (const float*)d_in[16];
  const float* offb = (const float*)d_in[17];
  const float* aw  = (const float*)d_in[18];
  const float* ab  = (const float*)d_in[19];
  const float* tw  = (const float*)d_in[20];
  const float* tb  = (const float*)d_in[21];
  const float* o1w = (const float*)d_in[22];
  const float* o1b = (const float*)d_in[23];
  const float* o2w = (const float*)d_in[24];
  const float* o2b = (const float*)d_in[25];
  const float* gate = (const float*)d_in[26];
  float* out = (float*)d_out;
  float* ws = (float*)d_ws;

  // workspace layout (f32 elements)
  float* vsb    = ws;                 // v in [(b,n,head)][yx][hd16] : 9437184
  float* qbuf   = ws +  9437184;      // q in [(b,head)][yx][hd16]  : 2359296 ; later reused as o1 mid
  float* netb   = ws + 11796480;      // net planar [hd][bh][yx]    : 2359296
  float* dwbuf  = ws + 14155776;      // depthwise out [b][c][yx]   : 2359296 ; later reused as outattn
  float* entbf  = ws + 18284544;      // per-head entropy [item]    :  147456
  float* tbbuf  = ws + 18432000;      // time bias (B,H,N)          :      64
  float* wtbuf  = ws + 18432064;      // 5 transposed weights       :   81920
  if (ws_size < 18513984ull * 4ull) return;   // ~74.1 MB required

  float* wt_q  = wtbuf;
  float* wt_v  = wtbuf + 16384;
  float* wt_pw = wtbuf + 32768;
  float* wt_o1 = wtbuf + 49152;
  float* wt_o2 = wtbuf + 65536;

  dim3 blk(256,1,1);
  // 0. transpose weights
  prep_k<<<dim3(64,5,1), blk, 0, stream>>>(qw, vw, pww, o1w, o2w, wtbuf);
  // 1. q = conv1x1(query)
  conv1x1_k<EP_QV><<<dim3(144,2,1), blk, 0, stream>>>(query, wt_q, qb, qbuf, nullptr);
  // 2. v = conv1x1(values), sampling-friendly layout
  conv1x1_k<EP_QV><<<dim3(144,8,1), blk, 0, stream>>>(values, wt_v, vb, vsb, nullptr);
  // 3. depthwise 7x7 + gelu
  dw_k<<<dim3(9216,1,1), blk, 0, stream>>>(query, dww, dwb, dwbuf);
  // 4. pointwise -> initial GRU state (planar); consumes dwbuf
  conv1x1_k<EP_NET><<<dim3(144,2,1), blk, 0, stream>>>(dwbuf, wt_pw, pwb, netb, nullptr);
  // 5. time bias
  tb_k<<<dim3(1,1,1), dim3(64,1,1), 0, stream>>>(time_enc, tw, tb, tbbuf);
  // 6. FUSED corr + 3x GRU + softmax/sampling/entropy -> outattn into dwbuf (now free)
  fused_k<<<dim3(576,1,1), blk, 0, stream>>>(qbuf, vsb, netb, relt,
                                             wih, whh, bih, bhh, offw, offb, aw, ab,
                                             tbbuf, dwbuf, entbf);
  // 7. entropy mean / confidence -> d_out tail (f32)
  ent_k<<<dim3(72,1,1), blk, 0, stream>>>(entbf, out);
  // 8. o1 + gelu: dwbuf -> qbuf (mid)
  conv1x1_k<EP_GELU><<<dim3(144,2,1), blk, 0, stream>>>(dwbuf, wt_o1, o1b, qbuf, nullptr);
  // 9. o2 * sigmoid(gate) -> f32 d_out
  conv1x1_k<EP_GATE><<<dim3(144,2,1), blk, 0, stream>>>(qbuf, wt_o2, o2b, out, gate);
}

// Round 5
// 771.584 us; speedup vs baseline: 3.3430x; 1.2915x over previous
//
#include <hip/hip_runtime.h>
#include <hip/hip_bf16.h>

typedef unsigned short u16;
typedef unsigned int   u32;

// Problem constants: B=2, N=4, C=128, HEADS=8, P=4, H=W=96, TC=64, ITERS=3, HD=16
constexpr int kHW = 9216;       // 96*96
constexpr int kM  = 147456;     // 16*9216 (item-major image stride in floats; also B*HEADS*HW items)

__device__ __forceinline__ float gelu_f(float v){ return 0.5f*v*(1.0f+erff(v*0.70710678118654752f)); }
__device__ __forceinline__ float sigm_f(float v){ return 1.0f/(1.0f+expf(-v)); }

struct Bilin { int i00,i10,i01,i11; float w00,w10,w01,w11; };

__device__ __forceinline__ Bilin make_bilin(int x, int y, float ox, float oy){
  float gx = fmaf((float)x, 2.0f/95.0f, -1.0f);
  float gy = fmaf((float)y, 2.0f/95.0f, -1.0f);
  float sgx = fminf(fmaxf(gx+ox,-1.0f),1.0f);
  float sgy = fminf(fmaxf(gy+oy,-1.0f),1.0f);
  float ix = (sgx+1.0f)*0.5f*95.0f;
  float iy = (sgy+1.0f)*0.5f*95.0f;
  float x0f = floorf(ix), y0f = floorf(iy);
  float wx = ix-x0f, wy = iy-y0f;
  int x0 = min(max((int)x0f,0),95), y0 = min(max((int)y0f,0),95);
  int x1 = min(x0+1,95), y1 = min(y0+1,95);
  Bilin b;
  b.i00=(y0*96+x0)*16; b.i10=(y0*96+x1)*16; b.i01=(y1*96+x0)*16; b.i11=(y1*96+x1)*16;
  float iwx=1.0f-wx, iwy=1.0f-wy;
  b.w00=iwx*iwy; b.w10=wx*iwy; b.w01=iwx*wy; b.w11=wx*wy;
  return b;
}

__device__ __forceinline__ void sample16(const float* __restrict__ vp, const Bilin& bl, float* __restrict__ o){
  const float4* p00 = (const float4*)(vp + bl.i00);
  const float4* p10 = (const float4*)(vp + bl.i10);
  const float4* p01 = (const float4*)(vp + bl.i01);
  const float4* p11 = (const float4*)(vp + bl.i11);
  #pragma unroll
  for (int g = 0; g < 4; ++g){
    float4 a=p00[g], b=p10[g], c=p01[g], d=p11[g];
    o[g*4+0] = a.x*bl.w00 + b.x*bl.w10 + c.x*bl.w01 + d.x*bl.w11;
    o[g*4+1] = a.y*bl.w00 + b.y*bl.w10 + c.y*bl.w01 + d.y*bl.w11;
    o[g*4+2] = a.z*bl.w00 + b.z*bl.w10 + c.z*bl.w01 + d.z*bl.w11;
    o[g*4+3] = a.w*bl.w00 + b.w*bl.w10 + c.w*bl.w01 + d.w*bl.w11;
  }
}

// ---------------- transpose the five (C,C) weight matrices into [c][o] f32 ----------------
__global__ __launch_bounds__(256) void prep_k(const float* __restrict__ qw, const float* __restrict__ vw,
    const float* __restrict__ pww, const float* __restrict__ o1w, const float* __restrict__ o2w,
    float* __restrict__ wt)
{
  const float* src = (blockIdx.y==0)?qw:(blockIdx.y==1)?vw:(blockIdx.y==2)?pww:(blockIdx.y==3)?o1w:o2w;
  float* d = wt + blockIdx.y*16384;
  int i = blockIdx.x*256 + threadIdx.x;   // grid.x = 64 -> i in [0,16384)
  int o = i & 127, c = i >> 7;
  d[i] = src[o*128 + c];                  // d[c*128+o] = w[o][c]
}

// ---------------- conv1x1 as register-tiled GEMM ----------------
// M=128 px x N=128 out per block, 256 threads, 8x8 per thread, K=128 in chunks of 16.
// ASRC: 0 = planar [c][px], 1 = item-major [bh][px][16] (heads align with k-chunks).
// EPI : 0 = item-major [bh][px][16] out, 1 = gelu planar, 2 = gate planar.
template<int ASRC, int EPI>
__global__ __launch_bounds__(256, 3) void gemm1x1_k(const float* __restrict__ inp,
    const float* __restrict__ wt, const float* __restrict__ bias,
    float* __restrict__ outf, const float* __restrict__ gate)
{
  __shared__ __align__(16) float a_s[16*132];
  __shared__ __align__(16) float b_s[16*132];
  const int tid = threadIdx.x;
  const int tx = tid & 15, ty = tid >> 4;
  const int img = blockIdx.y;
  const int px0 = blockIdx.x * 128;
  const int sr = tid >> 4;           // staging row 0..15
  const int sc = (tid & 15) * 8;     // staging col

  float acc[64];
  #pragma unroll
  for (int oj = 0; oj < 8; ++oj) {
    float bv = bias[tx*8+oj];
    #pragma unroll
    for (int pi = 0; pi < 8; ++pi) acc[pi*8+oj] = bv;
  }

  for (int kc = 0; kc < 8; ++kc) {
    const int k0 = kc*16;
    { const float4* g = (const float4*)(wt + (k0+sr)*128 + sc);
      float4 v0 = g[0], v1 = g[1];
      *(float4*)&b_s[sr*132+sc] = v0; *(float4*)&b_s[sr*132+sc+4] = v1; }
    if (ASRC == 0) {
      const float4* g = (const float4*)(inp + (size_t)(img*128 + k0 + sr)*kHW + px0 + sc);
      float4 v0 = g[0], v1 = g[1];
      *(float4*)&a_s[sr*132+sc] = v0; *(float4*)&a_s[sr*132+sc+4] = v1;
    } else {
      const int px = tid >> 1, hd0 = (tid & 1)*8;
      const float4* g = (const float4*)(inp + ((size_t)(img*8 + kc)*kHW + px0 + px)*16 + hd0);
      float4 v0 = g[0], v1 = g[1];
      a_s[(hd0+0)*132+px]=v0.x; a_s[(hd0+1)*132+px]=v0.y; a_s[(hd0+2)*132+px]=v0.z; a_s[(hd0+3)*132+px]=v0.w;
      a_s[(hd0+4)*132+px]=v1.x; a_s[(hd0+5)*132+px]=v1.y; a_s[(hd0+6)*132+px]=v1.z; a_s[(hd0+7)*132+px]=v1.w;
    }
    __syncthreads();
    #pragma unroll
    for (int k = 0; k < 16; ++k) {
      float4 b0 = *(const float4*)&b_s[k*132 + tx*8];
      float4 b1 = *(const float4*)&b_s[k*132 + tx*8 + 4];
      float4 a0 = *(const float4*)&a_s[k*132 + ty*8];
      float4 a1 = *(const float4*)&a_s[k*132 + ty*8 + 4];
      float av[8] = {a0.x,a0.y,a0.z,a0.w,a1.x,a1.y,a1.z,a1.w};
      float bv[8] = {b0.x,b0.y,b0.z,b0.w,b1.x,b1.y,b1.z,b1.w};
      #pragma unroll
      for (int pi = 0; pi < 8; ++pi)
        #pragma unroll
        for (int oj = 0; oj < 8; ++oj)
          acc[pi*8+oj] = fmaf(av[pi], bv[oj], acc[pi*8+oj]);
    }
    __syncthreads();
  }

  if (EPI == 0) {
    const int head = tx >> 1, hd0 = (tx & 1)*8;
    #pragma unroll
    for (int pi = 0; pi < 8; ++pi) {
      const int px = px0 + ty*8 + pi;
      float* dst = outf + ((size_t)(img*8 + head)*kHW + px)*16 + hd0;
      float4 t0 = {acc[pi*8+0],acc[pi*8+1],acc[pi*8+2],acc[pi*8+3]};
      float4 t1 = {acc[pi*8+4],acc[pi*8+5],acc[pi*8+6],acc[pi*8+7]};
      *(float4*)dst = t0; *(float4*)(dst+4) = t1;
    }
  } else {
    #pragma unroll
    for (int oj = 0; oj < 8; ++oj) {
      const int o = tx*8 + oj;
      float* dst = outf + (size_t)(img*128 + o)*kHW + px0 + ty*8;
      float v[8];
      #pragma unroll
      for (int pi = 0; pi < 8; ++pi) {
        float t = acc[pi*8+oj];
        v[pi] = (EPI == 1) ? gelu_f(t) : t * sigm_f(gate[o]);
      }
      float4 t0 = {v[0],v[1],v[2],v[3]};
      float4 t1 = {v[4],v[5],v[6],v[7]};
      *(float4*)dst = t0; *(float4*)(dst+4) = t1;
    }
  }
}

// ---------------- depthwise 7x7 + bias + exact gelu ----------------
__global__ __launch_bounds__(256) void dw_k(const float* __restrict__ q, const float* __restrict__ dww,
    const float* __restrict__ dwb, float* __restrict__ outf)
{
  int idx = blockIdx.x*256 + threadIdx.x;   // B*C*HW
  int px = idx % kHW;
  int bc = idx / kHW;
  int c = bc & 127;
  int x = px % 96, y = px / 96;
  float s = dwb[c];
  const float* qb = q + (size_t)bc*kHW;
  #pragma unroll
  for (int ky = 0; ky < 7; ++ky) {
    int yy = y + ky - 3;
    if (yy < 0 || yy > 95) continue;
    #pragma unroll
    for (int kx = 0; kx < 7; ++kx) {
      int xx = x + kx - 3;
      if (xx < 0 || xx > 95) continue;
      s = fmaf(qb[yy*96+xx], dww[c*49 + ky*7 + kx], s);
    }
  }
  outf[idx] = gelu_f(s);
}

// ---------------- time bias: (B,HEADS,N) ----------------
__global__ void tb_k(const float* __restrict__ te, const float* __restrict__ tw,
                     const float* __restrict__ tbias, float* __restrict__ tbb)
{
  int i = threadIdx.x;
  if (i >= 64) return;
  int b = i >> 5, h = (i >> 2) & 7, n = i & 3;
  float s = tbias[h];
  for (int tc = 0; tc < 64; ++tc) s = fmaf(te[(b*4+n)*64 + tc], tw[h*64+tc], s);
  tbb[(b*8+h)*4 + n] = s;
}

// ---------------- FUSED: correlation argmax + 3 GRU iterations + softmax/sampling/entropy ----
// net/out are item-major [item][16] (float4 IO). XCD-aware block swizzle for v L2 locality.
__global__ __launch_bounds__(256, 3) void fused_k(
    const float* __restrict__ qb, const float* __restrict__ vs,
    const float* __restrict__ netb, const float* __restrict__ relt,
    const float* __restrict__ wih, const float* __restrict__ whh,
    const float* __restrict__ bihp, const float* __restrict__ bhhp,
    const float* __restrict__ offw, const float* __restrict__ offbp,
    const float* __restrict__ aw, const float* __restrict__ abp,
    const float* __restrict__ tbb,
    float* __restrict__ outattn, float* __restrict__ entb)
{
  __shared__ __align__(16) float s_wih[48*20];   // rows padded 18->20 (pad=0)
  __shared__ __align__(16) float s_whh[48*16];
  __shared__ __align__(16) float s_offw[8*16];
  __shared__ __align__(16) float s_aw[4*16];
  __shared__ float s_bih[48], s_bhh[48], s_offb[8], s_ab[4];
  const int tid = threadIdx.x;
  for (int i = tid; i < 960; i += 256){ int g = i/20, k = i%20; s_wih[i] = (k<18)? wih[g*18+k] : 0.0f; }
  for (int i = tid; i < 768; i += 256) s_whh[i] = whh[i];
  if (tid < 128) s_offw[tid] = offw[tid];
  if (tid < 64)  s_aw[tid]  = aw[tid];
  if (tid < 48){ s_bih[tid] = bihp[tid]; s_bhh[tid] = bhhp[tid]; }
  if (tid < 8)   s_offb[tid] = offbp[tid];
  if (tid < 4)   s_ab[tid]  = abp[tid];

  // XCD swizzle: 576 blocks = 8 XCDs x 72; XCD x (round-robin assumption) gets virtual
  // blocks x*72..x*72+71 -> 2 contiguous bh groups -> ~4.6 MB v working set (~L2 size).
  const int vblk = (blockIdx.x & 7)*72 + (blockIdx.x >> 3);
  const int item = vblk*256 + tid;
  const int yx = item % kHW; const int bh = item / kHW;
  const int b = bh >> 3, head = bh & 7;
  const int x = yx % 96, y = yx / 96;
  int nidx = 0;
  { float bv = fabsf(relt[b*4]);
    for (int n = 1; n < 4; ++n){ float a = fabsf(relt[b*4+n]); if (a < bv){ bv=a; nidx=n; } } }
  const float* vp = vs + (size_t)((b*4+nidx)*8 + head)*kM;

  // ---- correlation argmax (f64 accumulation, matches numpy ordering) ----
  float off_[8], attn_[4];
  {
    float qv[16];
    { const float4* q4 = (const float4*)(qb + (size_t)bh*kM + yx*16);
      #pragma unroll
      for (int g = 0; g < 4; ++g){ float4 t = q4[g]; qv[g*4]=t.x; qv[g*4+1]=t.y; qv[g*4+2]=t.z; qv[g*4+3]=t.w; } }
    const int sdx[5] = {0,-1,1,0,0};   // SHIFTS entries are (dx,dy)
    const int sdy[5] = {0,0,0,-1,1};
    double bsc = 0.0; int best = 0;
    #pragma unroll
    for (int s5 = 0; s5 < 5; ++s5) {
      int sy = y - sdy[s5], sx = x - sdx[s5];
      double sc = 0.0;
      if (sy >= 0 && sy < 96 && sx >= 0 && sx < 96) {
        const float* tp = vp + (sy*96+sx)*16;
        #pragma unroll
        for (int hd = 0; hd < 16; ++hd) sc += (double)qv[hd]*(double)tp[hd];
      }
      if (s5 == 0) { bsc = sc; best = 0; }
      else if (sc > bsc) { bsc = sc; best = s5; }
    }
    const float STEP = 2.0f/96.0f;
    float ox = 0.f, oy = 0.f;        // reference swap: x-offset = dy*2/W, y-offset = dx*2/H
    if (best == 3) ox = -STEP; else if (best == 4) ox = STEP;
    if (best == 1) oy = -STEP; else if (best == 2) oy = STEP;
    #pragma unroll
    for (int p = 0; p < 4; ++p) { off_[2*p] = ox; off_[2*p+1] = oy; attn_[p] = 0.0f; }
  }

  float h[16];
  { const float4* n4 = (const float4*)(netb + (size_t)item*16);
    #pragma unroll
    for (int g = 0; g < 4; ++g){ float4 t = n4[g]; h[g*4]=t.x; h[g*4+1]=t.y; h[g*4+2]=t.z; h[g*4+3]=t.w; } }

  __syncthreads();   // LDS weights ready

  // ---- 3 GRU refinement iterations, all state in registers ----
  for (int it = 0; it < 3; ++it) {
    const float p0x = off_[0];
    const float p0y = off_[1];
    Bilin bl = make_bilin(x, y, p0x, p0y);
    float xv[20];
    sample16(vp, bl, xv);
    xv[16] = p0x; xv[17] = p0y; xv[18] = 0.f; xv[19] = 0.f;

    float hn[16];
    #pragma unroll 2
    for (int j = 0; j < 16; ++j) {
      float g0 = s_bih[j], g1 = s_bih[16+j], g2 = s_bih[32+j];
      const float4* w0r = (const float4*)&s_wih[j*20];
      const float4* w1r = (const float4*)&s_wih[(16+j)*20];
      const float4* w2r = (const float4*)&s_wih[(32+j)*20];
      #pragma unroll
      for (int q4 = 0; q4 < 5; ++q4) {
        float4 w0 = w0r[q4], w1 = w1r[q4], w2 = w2r[q4];
        float a0 = xv[q4*4+0], a1 = xv[q4*4+1], a2 = xv[q4*4+2], a3 = xv[q4*4+3];
        g0 = fmaf(a0,w0.x,g0); g0 = fmaf(a1,w0.y,g0); g0 = fmaf(a2,w0.z,g0); g0 = fmaf(a3,w0.w,g0);
        g1 = fmaf(a0,w1.x,g1); g1 = fmaf(a1,w1.y,g1); g1 = fmaf(a2,w1.z,g1); g1 = fmaf(a3,w1.w,g1);
        g2 = fmaf(a0,w2.x,g2); g2 = fmaf(a1,w2.y,g2); g2 = fmaf(a2,w2.z,g2); g2 = fmaf(a3,w2.w,g2);
      }
      float t0 = s_bhh[j], t1 = s_bhh[16+j], t2 = s_bhh[32+j];
      const float4* h0r = (const float4*)&s_whh[j*16];
      const float4* h1r = (const float4*)&s_whh[(16+j)*16];
      const float4* h2r = (const float4*)&s_whh[(32+j)*16];
      #pragma unroll
      for (int q4 = 0; q4 < 4; ++q4) {
        float4 w0 = h0r[q4], w1 = h1r[q4], w2 = h2r[q4];
        float a0 = h[q4*4+0], a1 = h[q4*4+1], a2 = h[q4*4+2], a3 = h[q4*4+3];
        t0 = fmaf(a0,w0.x,t0); t0 = fmaf(a1,w0.y,t0); t0 = fmaf(a2,w0.z,t0); t0 = fmaf(a3,w0.w,t0);
        t1 = fmaf(a0,w1.x,t1); t1 = fmaf(a1,w1.y,t1); t1 = fmaf(a2,w1.z,t1); t1 = fmaf(a3,w1.w,t1);
        t2 = fmaf(a0,w2.x,t2); t2 = fmaf(a1,w2.y,t2); t2 = fmaf(a2,w2.z,t2); t2 = fmaf(a3,w2.w,t2);
      }
      float r = sigm_f(g0 + t0);
      float z = sigm_f(g1 + t1);
      float nn = tanhf(fmaf(r, t2, g2));
      hn[j] = fmaf(z, h[j], (1.0f - z)*nn);
    }
    #pragma unroll
    for (int j = 0; j < 16; ++j) h[j] = hn[j];

    #pragma unroll
    for (int d = 0; d < 8; ++d) {
      const float4* wr = (const float4*)&s_offw[d*16];
      float s = s_offb[d];
      #pragma unroll
      for (int q4 = 0; q4 < 4; ++q4) {
        float4 w4 = wr[q4];
        s = fmaf(h[q4*4+0], w4.x, s); s = fmaf(h[q4*4+1], w4.y, s);
        s = fmaf(h[q4*4+2], w4.z, s); s = fmaf(h[q4*4+3], w4.w, s);
      }
      off_[d] += s;
    }
    #pragma unroll
    for (int p = 0; p < 4; ++p) {
      const float4* wr = (const float4*)&s_aw[p*16];
      float s = s_ab[p];
      #pragma unroll
      for (int q4 = 0; q4 < 4; ++q4) {
        float4 w4 = wr[q4];
        s = fmaf(h[q4*4+0], w4.x, s); s = fmaf(h[q4*4+1], w4.y, s);
        s = fmaf(h[q4*4+2], w4.z, s); s = fmaf(h[q4*4+3], w4.w, s);
      }
      attn_[p] += s;
    }
  }

  // ---- softmax over (N,P) + entropy ----
  float lg[16];
  #pragma unroll
  for (int n = 0; n < 4; ++n) {
    float tv = tbb[(b*8+head)*4 + n];
    #pragma unroll
    for (int p = 0; p < 4; ++p) lg[n*4+p] = attn_[p] + tv;
  }
  float mx = lg[0];
  #pragma unroll
  for (int i = 1; i < 16; ++i) mx = fmaxf(mx, lg[i]);
  float es = 0.f;
  #pragma unroll
  for (int i = 0; i < 16; ++i){ lg[i] = expf(lg[i]-mx); es += lg[i]; }
  float inv = 1.0f/es;
  float ent = 0.f;
  #pragma unroll
  for (int i = 0; i < 16; ++i){ lg[i] *= inv; ent -= lg[i]*logf(lg[i] + 1e-8f); }
  entb[item] = ent;

  // ---- N*P deformable sampling + weighted sum ----
  float acc[16];
  #pragma unroll
  for (int j = 0; j < 16; ++j) acc[j] = 0.f;
  #pragma unroll
  for (int p = 0; p < 4; ++p) {
    Bilin bl = make_bilin(x, y, off_[2*p], off_[2*p+1]);
    #pragma unroll
    for (int n = 0; n < 4; ++n) {
      const float* vpn = vs + (size_t)((b*4+n)*8 + head)*kM;
      float smp[16];
      sample16(vpn, bl, smp);
      float wnp = lg[n*4+p];
      #pragma unroll
      for (int j = 0; j < 16; ++j) acc[j] = fmaf(wnp, smp[j], acc[j]);
    }
  }
  float4* dst = (float4*)(outattn + (size_t)item*16);
  #pragma unroll
  for (int g = 0; g < 4; ++g) {
    float4 t = {acc[g*4+0],acc[g*4+1],acc[g*4+2],acc[g*4+3]};
    dst[g] = t;
  }
}

// ---------------- entropy mean over heads -> confidence/entropy outputs (f32) ----------------
__global__ __launch_bounds__(256) void ent_k(const float* __restrict__ entb, float* __restrict__ outf)
{
  int idx = blockIdx.x*256 + threadIdx.x;   // B*HW = 18432
  int b = idx / kHW, yx = idx % kHW;
  float s = 0.f;
  #pragma unroll
  for (int h8 = 0; h8 < 8; ++h8) s += entb[(b*8+h8)*kHW + yx];
  s *= 0.125f;
  float conf = 1.0f - fminf(fmaxf(s / (2.772588722239781f + 1e-8f), 0.0f), 1.0f);
  outf[2359296 + idx]         = conf;
  outf[2359296 + 18432 + idx] = s;
}

extern "C" void kernel_launch(void* const* d_in, const int* in_sizes, int n_in,
                              void* d_out, int out_size, void* d_ws, size_t ws_size,
                              hipStream_t stream)
{
  const float* query  = (const float*)d_in[0];
  const float* values = (const float*)d_in[1];
  const float* relt   = (const float*)d_in[2];
  const float* time_enc = (const float*)d_in[3];
  const float* qw  = (const float*)d_in[4];
  const float* qb  = (const float*)d_in[5];
  const float* vw  = (const float*)d_in[6];
  const float* vb  = (const float*)d_in[7];
  const float* dww = (const float*)d_in[8];
  const float* dwb = (const float*)d_in[9];
  const float* pww = (const float*)d_in[10];
  const float* pwb = (const float*)d_in[11];
  const float* wih = (const float*)d_in[12];
  const float* whh = (const float*)d_in[13];
  const float* bih = (const float*)d_in[14];
  const float* bhh = (const float*)d_in[15];
  const float* offw = (const float*)d_in[16];
  const float* offb = (const float*)d_in[17];
  const float* aw  = (const float*)d_in[18];
  const float* ab  = (const float*)d_in[19];
  const float* tw  = (const float*)d_in[20];
  const float* tb  = (const float*)d_in[21];
  const float* o1w = (const float*)d_in[22];
  const float* o1b = (const float*)d_in[23];
  const float* o2w = (const float*)d_in[24];
  const float* o2b = (const float*)d_in[25];
  const float* gate = (const float*)d_in[26];
  float* out = (float*)d_out;
  float* ws = (float*)d_ws;

  // workspace layout (f32 elements)
  float* vsb    = ws;                 // v item-major [(b,n,head)][yx][16] : 9437184
  float* qbuf   = ws +  9437184;      // q item-major [(b,head)][yx][16]   : 2359296 ; reused as o1 mid (planar)
  float* netb   = ws + 11796480;      // net item-major [bh][yx][16]       : 2359296
  float* dwbuf  = ws + 14155776;      // depthwise out planar [b][c][yx]   : 2359296 ; reused as outattn item-major
  float* entbf  = ws + 18284544;      // per-head entropy [item]           :  147456
  float* tbbuf  = ws + 18432000;      // time bias (B,H,N)                 :      64
  float* wtbuf  = ws + 18432064;      // 5 transposed weights              :   81920
  if (ws_size < 18513984ull * 4ull) return;   // ~74.1 MB required

  float* wt_q  = wtbuf;
  float* wt_v  = wtbuf + 16384;
  float* wt_pw = wtbuf + 32768;
  float* wt_o1 = wtbuf + 49152;
  float* wt_o2 = wtbuf + 65536;

  dim3 blk(256,1,1);
  // 0. transpose weights
  prep_k<<<dim3(64,5,1), blk, 0, stream>>>(qw, vw, pww, o1w, o2w, wtbuf);
  // 1. q = conv1x1(query) -> item-major qbuf
  gemm1x1_k<0,0><<<dim3(72,2,1), blk, 0, stream>>>(query, wt_q, qb, qbuf, nullptr);
  // 2. v = conv1x1(values) -> item-major vsb
  gemm1x1_k<0,0><<<dim3(72,8,1), blk, 0, stream>>>(values, wt_v, vb, vsb, nullptr);
  // 3. depthwise 7x7 + gelu -> planar dwbuf
  dw_k<<<dim3(9216,1,1), blk, 0, stream>>>(query, dww, dwb, dwbuf);
  // 4. pointwise -> initial GRU state, item-major netb; consumes dwbuf
  gemm1x1_k<0,0><<<dim3(72,2,1), blk, 0, stream>>>(dwbuf, wt_pw, pwb, netb, nullptr);
  // 5. time bias
  tb_k<<<dim3(1,1,1), dim3(64,1,1), 0, stream>>>(time_enc, tw, tb, tbbuf);
  // 6. FUSED corr + 3x GRU + softmax/sampling/entropy -> outattn (item-major) into dwbuf
  fused_k<<<dim3(576,1,1), blk, 0, stream>>>(qbuf, vsb, netb, relt,
                                             wih, whh, bih, bhh, offw, offb, aw, ab,
                                             tbbuf, dwbuf, entbf);
  // 7. entropy mean / confidence -> d_out tail (f32)
  ent_k<<<dim3(72,1,1), blk, 0, stream>>>(entbf, out);
  // 8. o1 + gelu: item-major dwbuf -> planar qbuf (mid)
  gemm1x1_k<1,1><<<dim3(72,2,1), blk, 0, stream>>>(dwbuf, wt_o1, o1b, qbuf, nullptr);
  // 9. o2 * sigmoid(gate): planar qbuf -> f32 d_out
  gemm1x1_k<0,2><<<dim3(72,2,1), blk, 0, stream>>>(qbuf, wt_o2, o2b, out, gate);
}